// Round 1
// 338.991 us; speedup vs baseline: 1.1006x; 1.1006x over previous
//
#include <hip/hip_runtime.h>

#define N_NODES 50000
#define N_EDGES 600000
#define F_NODE 128
#define F_EDGE 32
#define MSG 32
#define NPB 64          // nodes per fused block
#define QBLOCKS ((N_NODES + NPB - 1) / NPB)        // 782
#define CBLOCKS ((N_EDGES + 255) / 256)            // 2344

// bf16 helpers
__device__ __forceinline__ unsigned short f2bf(float f) {
    union { float f; unsigned int u; } v; v.f = f;
    unsigned int r = v.u + 0x7fffu + ((v.u >> 16) & 1u);
    return (unsigned short)(r >> 16);
}

// Raw barrier: lgkmcnt(0)-only fence + s_barrier. Unlike __syncthreads(),
// this does NOT drain vmcnt(0), so prefetched global loads stay in flight
// across the barrier (T3/T4 counted-vmcnt pattern). The trailing empty asm
// is a compiler fence so memory ops can't hoist above the s_barrier.
#define BAR_LGKM() do {                                           \
    asm volatile("s_waitcnt lgkmcnt(0)" ::: "memory");            \
    __builtin_amdgcn_s_barrier();                                 \
    asm volatile("" ::: "memory");                                \
} while (0)

// ---------------------------------------------------------------------------
// qcount: blocks [0,QBLOCKS) compute Q[n] = nf[n] @ We[128:256] -> bf16;
// blocks [QBLOCKS,..) do the degree histogram. (round-6/7/8 proven)
// ---------------------------------------------------------------------------
__global__ __launch_bounds__(256)
void qcount_kernel(const float* __restrict__ nf,
                   const float* __restrict__ We,     // [288][32]
                   const int* __restrict__ idx,      // [2][E]
                   unsigned short* __restrict__ Q,   // [N][32] bf16
                   int* __restrict__ deg)
{
    if (blockIdx.x >= QBLOCKS) {
        int e = (blockIdx.x - QBLOCKS) * 256 + threadIdx.x;
        if (e < N_EDGES) {
            int n = idx[e];
            if ((unsigned)n < (unsigned)N_NODES) atomicAdd(&deg[n], 1);
        }
        return;
    }
    __shared__ float sInT[32 * 64];
    __shared__ float sWeC[32 * 32];

    const int tid = threadIdx.x;
    const int n0b = blockIdx.x * NPB;
    const int ng = tid & 31;
    const int og = tid >> 5;

    float accp[2][4];
#pragma unroll
    for (int i = 0; i < 2; ++i)
#pragma unroll
        for (int j = 0; j < 4; ++j) accp[i][j] = 0.f;

    for (int kc = 0; kc < 4; ++kc) {
        __syncthreads();
        ((float4*)sWeC)[tid] = ((const float4*)(We + (128 + kc * 32) * MSG))[tid];
        {
            int nl = tid >> 2, q = tid & 3;
            int n = n0b + nl; if (n >= N_NODES) n = N_NODES - 1;
            const float4* src4 = (const float4*)(nf + (size_t)n * F_NODE + kc * 32);
#pragma unroll
            for (int h = 0; h < 2; ++h) {
                float4 v = src4[q * 2 + h];
                int kl = q * 8 + h * 4;
                sInT[(kl + 0) * 64 + nl] = v.x;
                sInT[(kl + 1) * 64 + nl] = v.y;
                sInT[(kl + 2) * 64 + nl] = v.z;
                sInT[(kl + 3) * 64 + nl] = v.w;
            }
        }
        __syncthreads();
#pragma unroll
        for (int k = 0; k < 32; ++k) {
            float2 m = *(const float2*)&sInT[k * 64 + 2 * ng];
            float4 w = *(const float4*)&sWeC[k * 32 + og * 4];
            accp[0][0] += m.x * w.x; accp[0][1] += m.x * w.y;
            accp[0][2] += m.x * w.z; accp[0][3] += m.x * w.w;
            accp[1][0] += m.y * w.x; accp[1][1] += m.y * w.y;
            accp[1][2] += m.y * w.z; accp[1][3] += m.y * w.w;
        }
    }
#pragma unroll
    for (int i = 0; i < 2; ++i) {
        int n = n0b + 2 * ng + i;
        if (n < N_NODES) {
            ushort4 o;
            o.x = f2bf(accp[i][0]); o.y = f2bf(accp[i][1]);
            o.z = f2bf(accp[i][2]); o.w = f2bf(accp[i][3]);
            *(ushort4*)(Q + (size_t)n * MSG + og * 4) = o;
        }
    }
}

// ---------------------------------------------------------------------------
// scan v2: in-place exclusive scan, 1 block x 1024. COALESCED tile loop
// (old version strided 196B/lane from one CU -> ~16x overfetch + latency
// chain). Per 1024-tile: wave shfl-scan + 16-wave LDS combine; next tile's
// loads prefetched one tile ahead and kept in flight via raw barriers.
// ---------------------------------------------------------------------------
__global__ __launch_bounds__(1024)
void scan_kernel(int* __restrict__ deg_cursor) {
    __shared__ int wsum[16];
    __shared__ int wpre[16];
    const int t = threadIdx.x;
    const int lane = t & 63;
    const int wid = t >> 6;
    const int NT = (N_NODES + 1023) / 1024;   // 49
    int run = 0;
    int vnext = deg_cursor[t];                 // tile 0 (t < N_NODES always)
    for (int tt = 0; tt < NT; ++tt) {
        int v = vnext;
        if (tt + 1 < NT) {
            int ni = (tt + 1) * 1024 + t;
            vnext = (ni < N_NODES) ? deg_cursor[ni] : 0;
        }
        // wave-inclusive scan
        int x = v;
#pragma unroll
        for (int d = 1; d < 64; d <<= 1) {
            int u = __shfl_up(x, (unsigned)d, 64);
            if (lane >= d) x += u;
        }
        if (lane == 63) wsum[wid] = x;
        BAR_LGKM();
        if (wid == 0) {
            int s = (lane < 16) ? wsum[lane] : 0;
#pragma unroll
            for (int d = 1; d < 16; d <<= 1) {
                int u = __shfl_up(s, (unsigned)d, 64);
                if (lane >= d) s += u;
            }
            if (lane < 16) wpre[lane] = s;     // inclusive over wave sums
        }
        BAR_LGKM();
        int wexcl = (wid > 0) ? wpre[wid - 1] : 0;
        int total = wpre[15];
        int gi = tt * 1024 + t;
        if (gi < N_NODES) deg_cursor[gi] = run + wexcl + (x - v);  // exclusive
        run += total;
        BAR_LGKM();                            // wsum/wpre reusable
    }
}

// ---------------------------------------------------------------------------
// scatter: edge ids into destination-sorted order; cursor[n] -> end offset.
// ---------------------------------------------------------------------------
__global__ void scatter_kernel(const int* __restrict__ idx, int* __restrict__ cursor,
                               int* __restrict__ perm) {
    int e = blockIdx.x * 256 + threadIdx.x;
    if (e < N_EDGES) {
        int n = idx[e];
        if ((unsigned)n >= (unsigned)N_NODES) n = 0;
        int p = atomicAdd(&cursor[n], 1);
        if ((unsigned)p < (unsigned)N_EDGES) perm[p] = e;
    }
}

// ---------------------------------------------------------------------------
// Fused kernel — ZERO atomics. One block = 64 nodes + all their edges.
// v2 (this round): software-pipelined chunk loop.
//  - All 4 per-chunk barriers are raw s_barrier + lgkmcnt(0) (no vmcnt
//    drain), so global gathers stay in flight across barriers.
//  - perm prefetched 2 chunks ahead; idx(n1)+ef row prefetched 1 chunk
//    ahead into registers (issued during staging, consumed next staging ->
//    a full chunk of compute hides HBM latency; no dependent-load stalls).
//  - Q gather hoisted to right after barrier B (hidden under the GEMM).
//  - sBuf (ef^T / msgT) XOR-swizzled in 16B units by (row>>3)&3: kills the
//    structural 4-way bank conflict in the segmented reduce (4 same-node
//    lanes read rows 8 apart; 256-float rows alias mod-32 banks). GEMM /
//    store accesses keep uniform-row-per-instr -> still conflict-free.
// LDS unchanged 43.5 KB -> 3 blocks/CU. Numerics bit-identical to v1.
// ---------------------------------------------------------------------------
__global__ __launch_bounds__(256, 3)
void fused_kernel(const float* __restrict__ nf,
                  const int* __restrict__ idx,      // [2][E]
                  const float* __restrict__ ef,     // [E][32]
                  const float* __restrict__ We,     // [288][32]
                  const float* __restrict__ be,     // [32]
                  const float* __restrict__ Wn,     // [160][128]
                  const float* __restrict__ bn,     // [128]
                  const int* __restrict__ perm,     // [E] sorted edge ids
                  const int* __restrict__ cursor,   // [N] end offsets
                  const unsigned short* __restrict__ Q,  // [N][32] bf16
                  float* __restrict__ out)          // [N][128]
{
    __shared__ float sBuf[32 * 256];          // ef^T / msgT / (sInT|sWn)
    __shared__ float sWeC[32 * 32];           // ph0 chunks, then We_bot
    __shared__ unsigned short sP0h[NPB * 40]; // bf16, stride 40 (16B rows)
    __shared__ int sOff[NPB + 1];
    __shared__ int sLn[256];
    __shared__ int sN1[256];

    const int tid = threadIdx.x;
    const int n0b = blockIdx.x * NPB;

    // per-node start offsets: sOff[i] = start of node n0b+i; sOff[NPB] = end
    if (tid <= NPB) {
        int nn = n0b + tid - 1;
        int v;
        if (nn < 0) v = 0;
        else { if (nn >= N_NODES) nn = N_NODES - 1; v = cursor[nn]; }
        if (v < 0) v = 0;
        if (v > N_EDGES) v = N_EDGES;
        sOff[tid] = v;
    }

    float* sInT = sBuf;          // [32][64]
    float* sWn  = sBuf + 2048;   // [32][128]

    // ================= Phase 0: P0 = nf@We[0:128] + be -> bf16 ============
    {
        const int ng = tid & 31, og0 = tid >> 5;
        float accp[2][4];
#pragma unroll
        for (int i = 0; i < 2; ++i)
#pragma unroll
            for (int j = 0; j < 4; ++j) accp[i][j] = 0.f;

        for (int kc = 0; kc < 4; ++kc) {
            __syncthreads();
            ((float4*)sWeC)[tid] = ((const float4*)(We + kc * 32 * MSG))[tid];
            {
                int nl = tid >> 2, q = tid & 3;
                int n = n0b + nl; if (n >= N_NODES) n = N_NODES - 1;
                const float4* src4 = (const float4*)(nf + (size_t)n * F_NODE + kc * 32);
#pragma unroll
                for (int h = 0; h < 2; ++h) {
                    float4 v = src4[q * 2 + h];
                    int kl = q * 8 + h * 4;
                    sInT[(kl + 0) * 64 + nl] = v.x;
                    sInT[(kl + 1) * 64 + nl] = v.y;
                    sInT[(kl + 2) * 64 + nl] = v.z;
                    sInT[(kl + 3) * 64 + nl] = v.w;
                }
            }
            __syncthreads();
#pragma unroll
            for (int k = 0; k < 32; ++k) {
                float2 m = *(const float2*)&sInT[k * 64 + 2 * ng];
                float4 w = *(const float4*)&sWeC[k * 32 + og0 * 4];
                accp[0][0] += m.x * w.x; accp[0][1] += m.x * w.y;
                accp[0][2] += m.x * w.z; accp[0][3] += m.x * w.w;
                accp[1][0] += m.y * w.x; accp[1][1] += m.y * w.y;
                accp[1][2] += m.y * w.z; accp[1][3] += m.y * w.w;
            }
        }
#pragma unroll
        for (int i = 0; i < 2; ++i)
#pragma unroll
            for (int j = 0; j < 4; ++j)
                sP0h[(2 * ng + i) * 40 + og0 * 4 + j] =
                    f2bf(accp[i][j] + be[og0 * 4 + j]);
    }

    __syncthreads();                                   // ph0 done with sWeC
    ((float4*)sWeC)[tid] = ((const float4*)(We + 256 * MSG))[tid];  // We_bot

    const int rs = sOff[0];
    const int re = sOff[NPB];

    // persistent per-thread message sums: thread = (node rnl, cols rq8..+7)
    float msum[8];
#pragma unroll
    for (int j = 0; j < 8; ++j) msum[j] = 0.f;
    const int rnl = tid >> 2;
    const int rq8 = (tid & 3) * 8;
    const int rx  = (tid & 3) << 2;      // reduce-phase bank swizzle

    const int eg = tid & 63;   // edges 4*eg..+3
    const int og = tid >> 6;   // cols og*8..+7 (wave-uniform)

    // ---- prefetch pipeline registers -------------------------------------
    int n1r = 0;                     // n1 for chunk i (arrived)
    int pe_next = 0, pe_next2 = 0;   // perm value for chunk i+1 / in flight i+2
    float4 efr[8];                   // ef row for chunk i (arrived)
#pragma unroll
    for (int q = 0; q < 8; ++q) efr[q] = make_float4(0.f, 0.f, 0.f, 0.f);

    if (rs < re) {
        // prologue: synchronous fetch for chunk 0, prefetch perm for chunk 1
        int e = rs + tid;
        int pe0 = 0;
        if (e < re) {
            pe0 = perm[e];
            if ((unsigned)pe0 >= (unsigned)N_EDGES) pe0 = 0;   // poison guard
            int tnode = idx[N_EDGES + pe0];
            if ((unsigned)tnode >= (unsigned)N_NODES) tnode = 0;
            n1r = tnode;
        }
        const float4* ef4 = (const float4*)(ef + (size_t)pe0 * F_EDGE);
#pragma unroll
        for (int q = 0; q < 8; ++q) efr[q] = ef4[q];
        int e1 = rs + 256 + tid;
        if (e1 < re) {
            int p = perm[e1];
            if ((unsigned)p >= (unsigned)N_EDGES) p = 0;
            pe_next = p;
        }
        pe_next2 = pe_next;          // bootstrap rotation for iter 0
    }

    // ================= Chunk loop =========================================
    for (int cs = rs; cs < re; cs += 256) {
        BAR_LGKM();        // (A) prev reduction reads done; We_bot visible
        pe_next = pe_next2;          // rotate (load issued a full chunk ago)
        {
            // ---- consume prefetched regs for chunk i ----
            sN1[tid] = n1r;
#pragma unroll
            for (int q = 0; q < 8; ++q) {
                float4 v = efr[q];
                int ctw = ((tid & ~3) ^ (((q >> 1) & 3) << 2)) + (tid & 3);
                int r0 = q * 4 * 256;
                sBuf[r0 +   0 + ctw] = v.x;
                sBuf[r0 + 256 + ctw] = v.y;
                sBuf[r0 + 512 + ctw] = v.z;
                sBuf[r0 + 768 + ctw] = v.w;
            }
            // ---- issue gathers for chunk i+1 (fly across whole chunk) ----
            int e1 = cs + 256 + tid;
            if (e1 < re) {
                int pe1 = pe_next;
                int tnode = idx[N_EDGES + pe1];
                if ((unsigned)tnode >= (unsigned)N_NODES) tnode = 0;
                n1r = tnode;
                const float4* ef4 = (const float4*)(ef + (size_t)pe1 * F_EDGE);
#pragma unroll
                for (int q = 0; q < 8; ++q) efr[q] = ef4[q];
            } else {
                n1r = 0;             // stale efr only feeds never-read msgT cols
            }
            // ---- issue perm for chunk i+2 ----
            int e2 = cs + 512 + tid;
            if (e2 < re) {
                int p = perm[e2];
                if ((unsigned)p >= (unsigned)N_EDGES) p = 0;
                pe_next2 = p;
            } else pe_next2 = 0;
            // ---- local node id via binary search in sOff ----
            int e = cs + tid;
            int ln = 0;
            if (e < re) {
                int lo = 0, hi = NPB;
#pragma unroll
                for (int s = 0; s < 6; ++s) {
                    int mid = (lo + hi) >> 1;
                    if (sOff[mid] <= e) lo = mid; else hi = mid;
                }
                ln = lo;
            }
            sLn[tid] = ln;
        }
        BAR_LGKM();        // (B) staging visible

        // Q gather hoisted: in flight during the GEMM below
        uint4 qv[4];
#pragma unroll
        for (int i = 0; i < 4; ++i) {
            int n1 = sN1[4 * eg + i];
            qv[i] = *(const uint4*)(Q + (size_t)n1 * MSG + og * 8);
        }

        float acc[4][8];
#pragma unroll
        for (int i = 0; i < 4; ++i)
#pragma unroll
            for (int j = 0; j < 8; ++j) acc[i][j] = 0.f;

        const float* weB = sWeC + og * 8;
#pragma unroll
        for (int k = 0; k < 32; ++k) {
            float4 m = *(const float4*)&sBuf[k * 256 +
                        ((4 * eg) ^ (((k >> 3) & 3) << 2))];      // swizzled, conflict-free
            float4 w0 = *(const float4*)&weB[k * 32];             // broadcast
            float4 w1 = *(const float4*)&weB[k * 32 + 4];
            float ma[4] = { m.x, m.y, m.z, m.w };
            float wv[8] = { w0.x, w0.y, w0.z, w0.w, w1.x, w1.y, w1.z, w1.w };
#pragma unroll
            for (int i = 0; i < 4; ++i)
#pragma unroll
                for (int j = 0; j < 8; ++j) acc[i][j] += ma[i] * wv[j];
        }

        BAR_LGKM();        // (C) all ef^T reads done; sBuf reusable

        // ---- +P0 +Q, relu, store msgT[col][edge] (b128 along edges) ----
        {
            uint4 pv[4];
#pragma unroll
            for (int i = 0; i < 4; ++i) {
                int ln = sLn[4 * eg + i];
                pv[i] = *(const uint4*)((const unsigned short*)sP0h + ln * 40 + og * 8);
            }
            int sb = (4 * eg) ^ (og << 2);       // (row>>3)&3 == og for all j
#pragma unroll
            for (int j = 0; j < 8; ++j) {
                float4 s;
                float sv[4];
#pragma unroll
                for (int i = 0; i < 4; ++i) {
                    unsigned qu = ((const unsigned*)&qv[i])[j >> 1];
                    unsigned pu = ((const unsigned*)&pv[i])[j >> 1];
                    float qf = __uint_as_float((j & 1) ? (qu & 0xffff0000u) : (qu << 16));
                    float pf = __uint_as_float((j & 1) ? (pu & 0xffff0000u) : (pu << 16));
                    sv[i] = fmaxf(acc[i][j] + pf + qf, 0.f);
                }
                s.x = sv[0]; s.y = sv[1]; s.z = sv[2]; s.w = sv[3];
                *(float4*)&sBuf[(og * 8 + j) * 256 + sb] = s;   // aligned, conflict-free
            }
        }
        BAR_LGKM();        // (D) msgT visible

        // ---- segmented reduction (no atomics): my node's range this chunk
        {
            int lo = sOff[rnl] - cs;     if (lo < 0) lo = 0;
            int hi = sOff[rnl + 1] - cs; if (hi > 256) hi = 256;
            for (int el = lo; el < hi; ++el) {
                int ebase = ((el & ~3) ^ rx) + (el & 3);   // 4 col-groups -> 4 banks
#pragma unroll
                for (int j = 0; j < 8; ++j)
                    msum[j] += sBuf[(rq8 + j) * 256 + ebase];
            }
        }
    }

    // ================= Phase 2: node GEMM (proven; kc=4 from msum) ========
    const int ng  = tid & 31;
    const int og2 = tid >> 5;

    float acc2[2][16];
#pragma unroll
    for (int i = 0; i < 2; ++i)
#pragma unroll
        for (int j = 0; j < 16; ++j) acc2[i][j] = 0.f;

    for (int kc = 0; kc < 5; ++kc) {
        __syncthreads();   // kc=0: last reduction reads done (full drain ok here)
        {
            const float4* w4 = (const float4*)(Wn + (size_t)kc * 32 * 128);
            float4* s4 = (float4*)sWn;
#pragma unroll
            for (int i = 0; i < 4; ++i) s4[tid + 256 * i] = w4[tid + 256 * i];
        }
        {
            int nl = tid >> 2, q = tid & 3;
            if (kc < 4) {
                int n = n0b + nl; if (n >= N_NODES) n = N_NODES - 1;
                const float4* src4 = (const float4*)(nf + (size_t)n * F_NODE + kc * 32);
#pragma unroll
                for (int h = 0; h < 2; ++h) {
                    float4 v = src4[q * 2 + h];
                    int kl = q * 8 + h * 4;
                    sInT[(kl + 0) * 64 + nl] = v.x;
                    sInT[(kl + 1) * 64 + nl] = v.y;
                    sInT[(kl + 2) * 64 + nl] = v.z;
                    sInT[(kl + 3) * 64 + nl] = v.w;
                }
            } else {
                // thread (nl, q) owns exactly msum for node nl, cols q*8..+7
#pragma unroll
                for (int h = 0; h < 8; ++h)
                    sInT[(q * 8 + h) * 64 + nl] = msum[h];
            }
        }
        __syncthreads();

#pragma unroll
        for (int k = 0; k < 32; ++k) {
            float2 m = *(const float2*)&sInT[k * 64 + 2 * ng];
            const float* wr = &sWn[k * 128 + og2 * 16];
            float4 w0 = *(const float4*)&wr[0];
            float4 w1 = *(const float4*)&wr[4];
            float4 w2 = *(const float4*)&wr[8];
            float4 w3 = *(const float4*)&wr[12];
            float ma[2] = { m.x, m.y };
            float wv[16] = { w0.x,w0.y,w0.z,w0.w, w1.x,w1.y,w1.z,w1.w,
                             w2.x,w2.y,w2.z,w2.w, w3.x,w3.y,w3.z,w3.w };
#pragma unroll
            for (int i = 0; i < 2; ++i)
#pragma unroll
                for (int j = 0; j < 16; ++j) acc2[i][j] += ma[i] * wv[j];
        }
    }

    float nbias[16];
#pragma unroll
    for (int j = 0; j < 16; ++j) nbias[j] = bn[og2 * 16 + j];

#pragma unroll
    for (int i = 0; i < 2; ++i) {
        int n = n0b + 2 * ng + i;
        if (n < N_NODES) {
            float* dst = out + (size_t)n * F_NODE + og2 * 16;
#pragma unroll
            for (int j = 0; j < 16; j += 4) {
                float4 v;
                v.x = fmaxf(acc2[i][j + 0] + nbias[j + 0], 0.f);
                v.y = fmaxf(acc2[i][j + 1] + nbias[j + 1], 0.f);
                v.z = fmaxf(acc2[i][j + 2] + nbias[j + 2], 0.f);
                v.w = fmaxf(acc2[i][j + 3] + nbias[j + 3], 0.f);
                *(float4*)(dst + j) = v;
            }
        }
    }
}

extern "C" void kernel_launch(void* const* d_in, const int* in_sizes, int n_in,
                              void* d_out, int out_size, void* d_ws, size_t ws_size,
                              hipStream_t stream) {
    const float* nf  = (const float*)d_in[0];
    const int*   idx = (const int*)d_in[1];
    const float* ef  = (const float*)d_in[2];
    const float* We  = (const float*)d_in[3];
    const float* be  = (const float*)d_in[4];
    const float* Wn  = (const float*)d_in[5];
    const float* bn  = (const float*)d_in[6];
    float* out = (float*)d_out;

    // ws: deg 0.2 MB + perm 2.4 MB + Q bf16 3.2 MB = 5.8 MB (confirmed safe)
    int* deg_cursor = (int*)d_ws;                          // 50000
    int* perm       = deg_cursor + N_NODES;                // 600000
    unsigned short* Q = (unsigned short*)(perm + N_EDGES); // [N][32] bf16

    hipMemsetAsync(deg_cursor, 0, (size_t)N_NODES * sizeof(int), stream);

    qcount_kernel<<<QBLOCKS + CBLOCKS, 256, 0, stream>>>(nf, We, idx, Q, deg_cursor);
    scan_kernel<<<1, 1024, 0, stream>>>(deg_cursor);
    scatter_kernel<<<CBLOCKS, 256, 0, stream>>>(idx, deg_cursor, perm);

    fused_kernel<<<QBLOCKS, 256, 0, stream>>>(
        nf, idx, ef, We, be, Wn, bn, perm, deg_cursor, Q, out);
}